// Round 2
// baseline (2948.143 us; speedup 1.0000x reference)
//
#include <hip/hip_runtime.h>
#include <math.h>

#define HID    128
#define NTREE  6000
#define NGRAPH 144000
#define NNODE  150000
#define NEDGE  600000
#define NSEG   4096
#define AF     34
#define EPSF   1e-8f

#define SCAN_BLK   256
#define SCAN_ELEMS 1024
#define NSCAN ((NNODE + SCAN_ELEMS - 1) / SCAN_ELEMS)   // 147

// ---------------- reductions ----------------

__device__ __forceinline__ float waveReduceSum(float v) {
#pragma unroll
  for (int o = 32; o > 0; o >>= 1) v += __shfl_down(v, o, 64);
  return v;
}

// block of exactly 128 threads (2 waves)
__device__ __forceinline__ float blockReduce128(float v, float* red) {
  v = waveReduceSum(v);
  int w = threadIdx.x >> 6;
  if ((threadIdx.x & 63) == 0) red[w] = v;
  __syncthreads();
  float r = red[0] + red[1];
  __syncthreads();
  return r;
}

// ---------------- CSR build ----------------

__global__ void k_hist(const int* __restrict__ dst, int* __restrict__ deg) {
  int e = blockIdx.x * blockDim.x + threadIdx.x;
  if (e < NEDGE) atomicAdd(&deg[dst[e]], 1);
}

__global__ void k_scan1(const int* __restrict__ deg, int* __restrict__ off,
                        int* __restrict__ part) {
  __shared__ int s[SCAN_BLK];
  int b = blockIdx.x, t = threadIdx.x;
  int base = b * SCAN_ELEMS + t * 4;
  int v0 = 0, v1 = 0, v2 = 0, v3 = 0;
  if (base + 0 < NNODE) v0 = deg[base + 0];
  if (base + 1 < NNODE) v1 = deg[base + 1];
  if (base + 2 < NNODE) v2 = deg[base + 2];
  if (base + 3 < NNODE) v3 = deg[base + 3];
  int sum = v0 + v1 + v2 + v3;
  s[t] = sum;
  __syncthreads();
  for (int o = 1; o < SCAN_BLK; o <<= 1) {
    int x = (t >= o) ? s[t - o] : 0;
    __syncthreads();
    s[t] += x;
    __syncthreads();
  }
  int run = s[t] - sum;  // exclusive prefix for this thread within block
  run += v0; if (base + 0 < NNODE) off[base + 1] = run;
  run += v1; if (base + 1 < NNODE) off[base + 2] = run;
  run += v2; if (base + 2 < NNODE) off[base + 3] = run;
  run += v3; if (base + 3 < NNODE) off[base + 4] = run;
  if (t == SCAN_BLK - 1) part[b] = s[t];
  if (b == 0 && t == 0) off[0] = 0;
}

__global__ void k_scan2(int* part, int nb) {
  __shared__ int s[SCAN_BLK];
  int t = threadIdx.x;
  s[t] = (t < nb) ? part[t] : 0;
  __syncthreads();
  for (int o = 1; o < SCAN_BLK; o <<= 1) {
    int x = (t >= o) ? s[t - o] : 0;
    __syncthreads();
    s[t] += x;
    __syncthreads();
  }
  if (t < nb) part[t] = s[t];
}

__global__ void k_scan3(int* __restrict__ off, const int* __restrict__ part) {
  int b = blockIdx.x;
  if (b == 0) return;
  int add = part[b - 1];
  int base = b * SCAN_ELEMS + threadIdx.x * 4 + 1;
#pragma unroll
  for (int j = 0; j < 4; j++) {
    int idx = base + j;
    if (idx <= NNODE) off[idx] += add;
  }
}

__global__ void k_fill(const int* __restrict__ dst, const int* __restrict__ src,
                       const float* __restrict__ ew, int* __restrict__ cur,
                       int* __restrict__ sperm, float* __restrict__ wperm) {
  int e = blockIdx.x * blockDim.x + threadIdx.x;
  if (e < NEDGE) {
    int d = dst[e];
    int p = atomicAdd(&cur[d], 1);
    sperm[p] = src[e];
    wperm[p] = ew[e];
  }
}

// ---------------- embedding (expmap0 + lorentz_linear W0) ----------------

__global__ void k_embed(const float* __restrict__ gfeat, const float* __restrict__ tfeat,
                        const float* __restrict__ W0, const float* __restrict__ b0,
                        const float* __restrict__ scale0, float* __restrict__ xout) {
  int row = blockIdx.x;
  int t = threadIdx.x;
  if (row < NTREE) {
    xout[row * HID + t] = tfeat[row * HID + t];
    return;
  }
  int g = row - NTREE;
  __shared__ float sp[AF];
  __shared__ float gfe[AF + 1];
  __shared__ float red[2];
  __shared__ float y0s;
  if (t < AF) sp[t] = gfeat[g * AF + t];
  __syncthreads();
  float ss = 0.f;
#pragma unroll
  for (int k = 0; k < AF; k++) { float x = sp[k]; ss += x * x; }
  float nrm = fmaxf(sqrtf(ss), EPSF);
  if (t == 0) gfe[0] = coshf(nrm);
  if (t < AF) gfe[t + 1] = sinhf(nrm) / nrm * sp[t];
  __syncthreads();
  float acc = b0[t];
  const float* wr = W0 + t * (AF + 1);
#pragma unroll
  for (int k = 0; k < AF + 1; k++) acc += wr[k] * gfe[k];
  if (t == 0) y0s = acc;
  __syncthreads();
  float escale = expf(scale0[0]);
  float timec = 1.f / (1.f + expf(-y0s)) * escale + 1.1f;
  float part = (t == 0) ? 0.f : acc * acc;
  float ssum = blockReduce128(part, red);
  float s = (timec * timec - 1.f) / fmaxf(ssum, EPSF);
  float sq = sqrtf(s);
  xout[row * HID + t] = (t == 0) ? timec : acc * sq;
}

// ---------------- lorentz_linear (128x128), register-tiled f32 ----------------
// Block 256 threads = 32 col-threads (tc) x 8 row-groups (rg).
// Thread computes 8 rows x 4 cols. Block tile: 64 rows x 128 cols.
// LDS: x chunk [64][32] (broadcast reads), W chunk [8][128][4] (permuted-contiguous).

template <int RELU>
__global__ __launch_bounds__(256, 4) void k_linear(const float* __restrict__ in,
                                                   const float* __restrict__ W,
                                                   const float* __restrict__ b,
                                                   const float* __restrict__ scale,
                                                   float* __restrict__ out) {
  __shared__ __align__(16) float xs[64 * 32];     // [row][k]  (8 KB)
  __shared__ __align__(16) float wl[8 * 128 * 4]; // [k4][col][4] (16 KB)

  const int tid = threadIdx.x;
  const int tc = tid & 31;        // col-thread
  const int rg = tid >> 5;        // row-group
  const int c0 = tc * 4;
  const int r0 = rg * 8;
  const int row_base = blockIdx.x * 64;

  float acc[8][4];
#pragma unroll
  for (int r = 0; r < 8; r++)
#pragma unroll
    for (int c = 0; c < 4; c++) acc[r][c] = 0.f;

  const int sr = tid >> 3;              // 0..31 (staging row)
  const int skx = (tid & 7) * 4;        // 0..28 (staging k)
  const int wcol = tid >> 1;            // 0..127
  const int wkh = (tid & 1) * 16;       // 0 or 16

  for (int kc = 0; kc < 4; ++kc) {
    __syncthreads();
    // stage x (64 rows x 32 k)
#pragma unroll
    for (int it = 0; it < 2; ++it) {
      int row = row_base + sr + it * 32;
      float4 v = make_float4(0.f, 0.f, 0.f, 0.f);
      if (row < NNODE) v = *(const float4*)&in[(size_t)row * HID + kc * 32 + skx];
      if (RELU) {
        v.x = fmaxf(v.x, 0.f); v.y = fmaxf(v.y, 0.f);
        v.z = fmaxf(v.z, 0.f); v.w = fmaxf(v.w, 0.f);
      }
      *(float4*)&xs[(sr + it * 32) * 32 + skx] = v;
    }
    // stage W (128 cols x 32 k) into [k4][col][4]
    {
      const float* wsrc = W + (size_t)wcol * HID + kc * 32 + wkh;
#pragma unroll
      for (int q = 0; q < 4; ++q) {
        float4 v = *(const float4*)&wsrc[q * 4];
        int k4 = (wkh >> 2) + q;
        *(float4*)&wl[(k4 * 128 + wcol) * 4] = v;
      }
    }
    __syncthreads();
    // compute: 8 k4-steps
#pragma unroll
    for (int k4 = 0; k4 < 8; ++k4) {
      float4 wv[4];
      float4 xv[8];
#pragma unroll
      for (int c = 0; c < 4; ++c)
        wv[c] = *(const float4*)&wl[(k4 * 128 + c0 + c) * 4];
#pragma unroll
      for (int r = 0; r < 8; ++r)
        xv[r] = *(const float4*)&xs[(r0 + r) * 32 + k4 * 4];
#pragma unroll
      for (int r = 0; r < 8; ++r)
#pragma unroll
        for (int c = 0; c < 4; ++c)
          acc[r][c] += wv[c].x * xv[r].x + wv[c].y * xv[r].y +
                       wv[c].z * xv[r].z + wv[c].w * xv[r].w;
    }
  }

  // epilogue: per-row lorentz normalization
  const float escale = expf(scale[0]);
  const float4 bb = *(const float4*)&b[c0];
#pragma unroll
  for (int r = 0; r < 8; ++r) {
    float y0v = acc[r][0] + bb.x;
    float y1v = acc[r][1] + bb.y;
    float y2v = acc[r][2] + bb.z;
    float y3v = acc[r][3] + bb.w;
    float part = y0v * y0v + y1v * y1v + y2v * y2v + y3v * y3v;
#pragma unroll
    for (int m = 1; m <= 16; m <<= 1) part += __shfl_xor(part, m, 64);
    // y at col 0 lives in tc==0's y0v; lane (lane&32) is tc==0 of my rg-half
    float y0 = __shfl(y0v, (threadIdx.x & 32), 64);
    float timec = 1.f / (1.f + expf(-y0)) * escale + 1.1f;
    float ssum = part - y0 * y0;
    float s = (timec * timec - 1.f) / fmaxf(ssum, EPSF);
    float sq = sqrtf(s);
    int row = row_base + r0 + r;
    if (row < NNODE) {
      float4 o;
      o.x = (tc == 0) ? timec : y0v * sq;
      o.y = y1v * sq;
      o.z = y2v * sq;
      o.w = y3v * sq;
      *(float4*)&out[(size_t)row * HID + c0] = o;
    }
  }
}

// ---------------- CSR gather + fused centroid normalize ----------------

__global__ void k_gather(const float* __restrict__ h, const int* __restrict__ off,
                         const int* __restrict__ sperm, const float* __restrict__ wperm,
                         float* __restrict__ out) {
  __shared__ float red[2];
  int n = blockIdx.x;
  int t = threadIdx.x;
  int e0 = off[n], e1 = off[n + 1];
  float acc = 0.f;
  for (int e = e0; e < e1; ++e) {
    int s = sperm[e];
    float w = wperm[e];
    acc += w * h[(size_t)s * HID + t];
  }
  float part = (t == 0) ? acc * acc : -acc * acc;
  float d = blockReduce128(part, red);
  float denom = sqrtf(fmaxf(fabsf(d), EPSF));
  out[(size_t)n * HID + t] = acc / denom;
}

// ---------------- final segment mean + normalize ----------------

__device__ __forceinline__ int lowerBound(const int* __restrict__ a, int n, int key) {
  int lo = 0, hi = n;
  while (lo < hi) {
    int mid = (lo + hi) >> 1;
    if (a[mid] < key) lo = mid + 1; else hi = mid;
  }
  return lo;
}

__global__ void k_final(const float* __restrict__ h, const int* __restrict__ seg,
                        float* __restrict__ out) {
  __shared__ float red[2];
  int bseg = blockIdx.x;
  int t = threadIdx.x;
  int lo = lowerBound(seg, NGRAPH, bseg);
  int hi = lowerBound(seg, NGRAPH, bseg + 1);
  float acc = 0.f;
  for (int r = lo; r < hi; ++r) acc += h[(size_t)(NTREE + r) * HID + t];
  float cnt = (float)(hi - lo);
  float ave = acc / fmaxf(cnt, 1.f);
  float part = (t == 0) ? ave * ave : -ave * ave;
  float d = blockReduce128(part, red);
  float denom = sqrtf(fmaxf(fabsf(d), EPSF));
  out[bseg * HID + t] = ave / denom;
}

// ---------------- launch ----------------

extern "C" void kernel_launch(void* const* d_in, const int* in_sizes, int n_in,
                              void* d_out, int out_size, void* d_ws, size_t ws_size,
                              hipStream_t stream) {
  const float* gfeat  = (const float*)d_in[0];
  const float* tfeat  = (const float*)d_in[1];
  const float* ew     = (const float*)d_in[2];
  const float* W0     = (const float*)d_in[3];
  const float* b0     = (const float*)d_in[4];
  const float* scale0 = (const float*)d_in[5];
  const float* Wl     = (const float*)d_in[6];
  const float* bl     = (const float*)d_in[7];
  const float* scalel = (const float*)d_in[8];
  const int* esrc     = (const int*)d_in[9];
  const int* edst     = (const int*)d_in[10];
  const int* segids   = (const int*)d_in[11];
  float* outp = (float*)d_out;

  char* ws = (char*)d_ws;
  size_t o = 0;
  auto take = [&](size_t bytes) -> char* {
    char* p = ws + o;
    o = (o + bytes + 255) & ~(size_t)255;
    return p;
  };
  int*   off   = (int*)take((NNODE + 1) * sizeof(int));
  int*   cur   = (int*)take(NNODE * sizeof(int));
  int*   sperm = (int*)take(NEDGE * sizeof(int));
  float* wperm = (float*)take(NEDGE * sizeof(float));
  int*   part  = (int*)take(SCAN_BLK * sizeof(int));
  float* bufA  = (float*)take((size_t)NNODE * HID * sizeof(float));
  float* bufB  = (float*)take((size_t)NNODE * HID * sizeof(float));
  (void)ws_size; (void)in_sizes; (void)n_in; (void)out_size;

  // CSR build (by destination)
  hipMemsetAsync(cur, 0, NNODE * sizeof(int), stream);
  k_hist<<<(NEDGE + 255) / 256, 256, 0, stream>>>(edst, cur);
  k_scan1<<<NSCAN, SCAN_BLK, 0, stream>>>(cur, off, part);
  k_scan2<<<1, SCAN_BLK, 0, stream>>>(part, NSCAN);
  k_scan3<<<NSCAN, SCAN_BLK, 0, stream>>>(off, part);
  hipMemcpyAsync(cur, off, NNODE * sizeof(int), hipMemcpyDeviceToDevice, stream);
  k_fill<<<(NEDGE + 255) / 256, 256, 0, stream>>>(edst, esrc, ew, cur, sperm, wperm);

  // initial node features
  k_embed<<<NNODE, 128, 0, stream>>>(gfeat, tfeat, W0, b0, scale0, bufA);

  // 3 message-passing layers
  for (int i = 0; i < 3; i++) {
    const float* Wi = Wl + (size_t)i * HID * HID;
    const float* bi = bl + (size_t)i * HID;
    const float* si = scalel + i;
    if (i == 0)
      k_linear<0><<<(NNODE + 63) / 64, 256, 0, stream>>>(bufA, Wi, bi, si, bufB);
    else
      k_linear<1><<<(NNODE + 63) / 64, 256, 0, stream>>>(bufA, Wi, bi, si, bufB);
    k_gather<<<NNODE, 128, 0, stream>>>(bufB, off, sperm, wperm, bufA);
  }

  // segment mean + normalize
  k_final<<<NSEG, 128, 0, stream>>>(bufA, segids, outp);
}

// Round 5
// 1040.527 us; speedup vs baseline: 2.8333x; 2.8333x over previous
//
#include <hip/hip_runtime.h>
#include <math.h>

#define HID    128
#define NTREE  6000
#define NGRAPH 144000
#define NNODE  150000
#define NEDGE  600000
#define NSEG   4096
#define AF     34
#define EPSF   1e-8f

#define SCAN_BLK   256
#define SCAN_ELEMS 1024
#define NSCAN ((NNODE + SCAN_ELEMS - 1) / SCAN_ELEMS)   // 147

// ---------------- reductions ----------------

__device__ __forceinline__ float waveReduceSum(float v) {
#pragma unroll
  for (int o = 32; o > 0; o >>= 1) v += __shfl_down(v, o, 64);
  return v;
}

// block of exactly 128 threads (2 waves)
__device__ __forceinline__ float blockReduce128(float v, float* red) {
  v = waveReduceSum(v);
  int w = threadIdx.x >> 6;
  if ((threadIdx.x & 63) == 0) red[w] = v;
  __syncthreads();
  float r = red[0] + red[1];
  __syncthreads();
  return r;
}

// ---------------- CSR build ----------------

__global__ void k_hist(const int* __restrict__ dst, int* __restrict__ deg) {
  int e = blockIdx.x * blockDim.x + threadIdx.x;
  if (e < NEDGE) atomicAdd(&deg[dst[e]], 1);
}

__global__ void k_scan1(const int* __restrict__ deg, int* __restrict__ off,
                        int* __restrict__ part) {
  __shared__ int s[SCAN_BLK];
  int b = blockIdx.x, t = threadIdx.x;
  int base = b * SCAN_ELEMS + t * 4;
  int v0 = 0, v1 = 0, v2 = 0, v3 = 0;
  if (base + 0 < NNODE) v0 = deg[base + 0];
  if (base + 1 < NNODE) v1 = deg[base + 1];
  if (base + 2 < NNODE) v2 = deg[base + 2];
  if (base + 3 < NNODE) v3 = deg[base + 3];
  int sum = v0 + v1 + v2 + v3;
  s[t] = sum;
  __syncthreads();
  for (int o = 1; o < SCAN_BLK; o <<= 1) {
    int x = (t >= o) ? s[t - o] : 0;
    __syncthreads();
    s[t] += x;
    __syncthreads();
  }
  int run = s[t] - sum;  // exclusive prefix for this thread within block
  run += v0; if (base + 0 < NNODE) off[base + 1] = run;
  run += v1; if (base + 1 < NNODE) off[base + 2] = run;
  run += v2; if (base + 2 < NNODE) off[base + 3] = run;
  run += v3; if (base + 3 < NNODE) off[base + 4] = run;
  if (t == SCAN_BLK - 1) part[b] = s[t];
  if (b == 0 && t == 0) off[0] = 0;
}

__global__ void k_scan2(int* part, int nb) {
  __shared__ int s[SCAN_BLK];
  int t = threadIdx.x;
  s[t] = (t < nb) ? part[t] : 0;
  __syncthreads();
  for (int o = 1; o < SCAN_BLK; o <<= 1) {
    int x = (t >= o) ? s[t - o] : 0;
    __syncthreads();
    s[t] += x;
    __syncthreads();
  }
  if (t < nb) part[t] = s[t];
}

__global__ void k_scan3(int* __restrict__ off, const int* __restrict__ part) {
  int b = blockIdx.x;
  if (b == 0) return;
  int add = part[b - 1];
  int base = b * SCAN_ELEMS + threadIdx.x * 4 + 1;
#pragma unroll
  for (int j = 0; j < 4; j++) {
    int idx = base + j;
    if (idx <= NNODE) off[idx] += add;
  }
}

__global__ void k_fill(const int* __restrict__ dst, const int* __restrict__ src,
                       const float* __restrict__ ew, int* __restrict__ cur,
                       int* __restrict__ sperm, float* __restrict__ wperm) {
  int e = blockIdx.x * blockDim.x + threadIdx.x;
  if (e < NEDGE) {
    int d = dst[e];
    int p = atomicAdd(&cur[d], 1);
    sperm[p] = src[e];
    wperm[p] = ew[e];
  }
}

// ---------------- embedding (expmap0 + lorentz_linear W0) ----------------

__global__ void k_embed(const float* __restrict__ gfeat, const float* __restrict__ tfeat,
                        const float* __restrict__ W0, const float* __restrict__ b0,
                        const float* __restrict__ scale0, float* __restrict__ xout) {
  int row = blockIdx.x;
  int t = threadIdx.x;
  if (row < NTREE) {
    xout[row * HID + t] = tfeat[row * HID + t];
    return;
  }
  int g = row - NTREE;
  __shared__ float sp[AF];
  __shared__ float gfe[AF + 1];
  __shared__ float red[2];
  __shared__ float y0s;
  if (t < AF) sp[t] = gfeat[g * AF + t];
  __syncthreads();
  float ss = 0.f;
#pragma unroll
  for (int k = 0; k < AF; k++) { float x = sp[k]; ss += x * x; }
  float nrm = fmaxf(sqrtf(ss), EPSF);
  if (t == 0) gfe[0] = coshf(nrm);
  if (t < AF) gfe[t + 1] = sinhf(nrm) / nrm * sp[t];
  __syncthreads();
  float acc = b0[t];
  const float* wr = W0 + t * (AF + 1);
#pragma unroll
  for (int k = 0; k < AF + 1; k++) acc += wr[k] * gfe[k];
  if (t == 0) y0s = acc;
  __syncthreads();
  float escale = expf(scale0[0]);
  float timec = 1.f / (1.f + expf(-y0s)) * escale + 1.1f;
  float part = (t == 0) ? 0.f : acc * acc;
  float ssum = blockReduce128(part, red);
  float s = (timec * timec - 1.f) / fmaxf(ssum, EPSF);
  float sq = sqrtf(s);
  xout[row * HID + t] = (t == 0) ? timec : acc * sq;
}

// ---------------- lorentz_linear (128x128), register-tiled f32 ----------------
// Block 256 threads = 32 col-threads (tc, 4 cols each) x 8 row-groups (rg, 4 rows
// each). Block tile: 32 rows x 128 cols. Per-thread acc 4x4 = 16 VGPRs (no spill;
// round-2 8x4 tile + __launch_bounds__(256,4) spilled: VGPR=64, WRITE 1.8GB).
// LDS W layout: [col][32] with quad-slot XOR swizzle (k4 ^ ((col>>2)&7)) so a
// wave's 4 W-reads per k4-step cover all 32 banks (round-2 [k4][col][4] hit only
// banks {0,16} -> 16-way conflict, 1.56e7 SQ_LDS_BANK_CONFLICT).
// x-tile reads are half-wave broadcasts (conflict-free by definition).

template <int RELU>
__global__ __launch_bounds__(256) void k_linear(const float* __restrict__ in,
                                                const float* __restrict__ W,
                                                const float* __restrict__ b,
                                                const float* __restrict__ scale,
                                                float* __restrict__ out) {
  __shared__ __align__(16) float xs[32 * 32];   // [row][k]  4 KB
  __shared__ __align__(16) float wl[128 * 32];  // [col][k-swizzled] 16 KB

  const int tid = threadIdx.x;
  const int tc = tid & 31;        // col-thread: owns cols 4*tc .. 4*tc+3
  const int rg = tid >> 5;        // row-group: owns rows 4*rg .. 4*rg+3
  const int c0 = tc * 4;
  const int r0 = rg * 4;
  const int row_base = blockIdx.x * 32;
  const int swz = tc & 7;         // reader-side swizzle key

  float acc[4][4];
#pragma unroll
  for (int r = 0; r < 4; r++)
#pragma unroll
    for (int c = 0; c < 4; c++) acc[r][c] = 0.f;

  const int sr  = tid >> 3;         // 0..31 (staging row)
  const int skx = (tid & 7) * 4;    // 0..28 (staging k)
  const int wcol = tid >> 1;        // 0..127
  const int wq0  = (tid & 1) * 4;   // first k-quad this thread stages (0 or 4)
  const int wswz = (wcol >> 2) & 7; // writer-side swizzle key (== reader's tc&7)

  for (int kc = 0; kc < 4; ++kc) {
    __syncthreads();
    // stage x: 32 rows x 32 k (coalesced 128B per 8 lanes)
    {
      int row = row_base + sr;
      float4 v = make_float4(0.f, 0.f, 0.f, 0.f);
      if (row < NNODE) v = *(const float4*)&in[(size_t)row * HID + kc * 32 + skx];
      if (RELU) {
        v.x = fmaxf(v.x, 0.f); v.y = fmaxf(v.y, 0.f);
        v.z = fmaxf(v.z, 0.f); v.w = fmaxf(v.w, 0.f);
      }
      *(float4*)&xs[sr * 32 + skx] = v;
    }
    // stage W: 128 cols x 32 k, swizzled quad slots
    {
      const float* wsrc = W + (size_t)wcol * HID + kc * 32 + wq0 * 4;
#pragma unroll
      for (int q = 0; q < 4; ++q) {
        float4 v = *(const float4*)&wsrc[q * 4];
        int k4 = wq0 + q;
        *(float4*)&wl[wcol * 32 + ((k4 ^ wswz) << 2)] = v;
      }
    }
    __syncthreads();
    // compute: 8 k4-steps, 64 FMA per step per thread
#pragma unroll
    for (int k4 = 0; k4 < 8; ++k4) {
      float4 xv[4];
      float4 wv[4];
#pragma unroll
      for (int r = 0; r < 4; ++r)
        xv[r] = *(const float4*)&xs[(r0 + r) * 32 + k4 * 4];
#pragma unroll
      for (int c = 0; c < 4; ++c)
        wv[c] = *(const float4*)&wl[(c0 + c) * 32 + ((k4 ^ swz) << 2)];
#pragma unroll
      for (int r = 0; r < 4; ++r)
#pragma unroll
        for (int c = 0; c < 4; ++c)
          acc[r][c] += wv[c].x * xv[r].x + wv[c].y * xv[r].y +
                       wv[c].z * xv[r].z + wv[c].w * xv[r].w;
    }
  }

  // epilogue: per-row lorentz normalization (reduce across the 32 tc lanes)
  const float escale = expf(scale[0]);
  const float4 bb = *(const float4*)&b[c0];
#pragma unroll
  for (int r = 0; r < 4; ++r) {
    float y0v = acc[r][0] + bb.x;
    float y1v = acc[r][1] + bb.y;
    float y2v = acc[r][2] + bb.z;
    float y3v = acc[r][3] + bb.w;
    float part = y0v * y0v + y1v * y1v + y2v * y2v + y3v * y3v;
#pragma unroll
    for (int m = 1; m <= 16; m <<= 1) part += __shfl_xor(part, m, 64);
    // col 0 lives in tc==0 of my half-wave
    float y0 = __shfl(y0v, (threadIdx.x & 32), 64);
    float timec = 1.f / (1.f + expf(-y0)) * escale + 1.1f;
    float ssum = part - y0 * y0;
    float s = (timec * timec - 1.f) / fmaxf(ssum, EPSF);
    float sq = sqrtf(s);
    int row = row_base + r0 + r;
    if (row < NNODE) {
      float4 o;
      o.x = (tc == 0) ? timec : y0v * sq;
      o.y = y1v * sq;
      o.z = y2v * sq;
      o.w = y3v * sq;
      *(float4*)&out[(size_t)row * HID + c0] = o;
    }
  }
}

// ---------------- CSR gather + fused centroid normalize ----------------

__global__ void k_gather(const float* __restrict__ h, const int* __restrict__ off,
                         const int* __restrict__ sperm, const float* __restrict__ wperm,
                         float* __restrict__ out) {
  __shared__ float red[2];
  int n = blockIdx.x;
  int t = threadIdx.x;
  int e0 = off[n], e1 = off[n + 1];
  float acc = 0.f;
  for (int e = e0; e < e1; ++e) {
    int s = sperm[e];
    float w = wperm[e];
    acc += w * h[(size_t)s * HID + t];
  }
  float part = (t == 0) ? acc * acc : -acc * acc;
  float d = blockReduce128(part, red);
  float denom = sqrtf(fmaxf(fabsf(d), EPSF));
  out[(size_t)n * HID + t] = acc / denom;
}

// ---------------- final segment mean + normalize ----------------

__device__ __forceinline__ int lowerBound(const int* __restrict__ a, int n, int key) {
  int lo = 0, hi = n;
  while (lo < hi) {
    int mid = (lo + hi) >> 1;
    if (a[mid] < key) lo = mid + 1; else hi = mid;
  }
  return lo;
}

__global__ void k_final(const float* __restrict__ h, const int* __restrict__ seg,
                        float* __restrict__ out) {
  __shared__ float red[2];
  int bseg = blockIdx.x;
  int t = threadIdx.x;
  int lo = lowerBound(seg, NGRAPH, bseg);
  int hi = lowerBound(seg, NGRAPH, bseg + 1);
  float acc = 0.f;
  for (int r = lo; r < hi; ++r) acc += h[(size_t)(NTREE + r) * HID + t];
  float cnt = (float)(hi - lo);
  float ave = acc / fmaxf(cnt, 1.f);
  float part = (t == 0) ? ave * ave : -ave * ave;
  float d = blockReduce128(part, red);
  float denom = sqrtf(fmaxf(fabsf(d), EPSF));
  out[bseg * HID + t] = ave / denom;
}

// ---------------- launch ----------------

extern "C" void kernel_launch(void* const* d_in, const int* in_sizes, int n_in,
                              void* d_out, int out_size, void* d_ws, size_t ws_size,
                              hipStream_t stream) {
  const float* gfeat  = (const float*)d_in[0];
  const float* tfeat  = (const float*)d_in[1];
  const float* ew     = (const float*)d_in[2];
  const float* W0     = (const float*)d_in[3];
  const float* b0     = (const float*)d_in[4];
  const float* scale0 = (const float*)d_in[5];
  const float* Wl     = (const float*)d_in[6];
  const float* bl     = (const float*)d_in[7];
  const float* scalel = (const float*)d_in[8];
  const int* esrc     = (const int*)d_in[9];
  const int* edst     = (const int*)d_in[10];
  const int* segids   = (const int*)d_in[11];
  float* outp = (float*)d_out;

  char* ws = (char*)d_ws;
  size_t o = 0;
  auto take = [&](size_t bytes) -> char* {
    char* p = ws + o;
    o = (o + bytes + 255) & ~(size_t)255;
    return p;
  };
  int*   off   = (int*)take((NNODE + 1) * sizeof(int));
  int*   cur   = (int*)take(NNODE * sizeof(int));
  int*   sperm = (int*)take(NEDGE * sizeof(int));
  float* wperm = (float*)take(NEDGE * sizeof(float));
  int*   part  = (int*)take(SCAN_BLK * sizeof(int));
  float* bufA  = (float*)take((size_t)NNODE * HID * sizeof(float));
  float* bufB  = (float*)take((size_t)NNODE * HID * sizeof(float));
  (void)ws_size; (void)in_sizes; (void)n_in; (void)out_size;

  // CSR build (by destination)
  hipMemsetAsync(cur, 0, NNODE * sizeof(int), stream);
  k_hist<<<(NEDGE + 255) / 256, 256, 0, stream>>>(edst, cur);
  k_scan1<<<NSCAN, SCAN_BLK, 0, stream>>>(cur, off, part);
  k_scan2<<<1, SCAN_BLK, 0, stream>>>(part, NSCAN);
  k_scan3<<<NSCAN, SCAN_BLK, 0, stream>>>(off, part);
  hipMemcpyAsync(cur, off, NNODE * sizeof(int), hipMemcpyDeviceToDevice, stream);
  k_fill<<<(NEDGE + 255) / 256, 256, 0, stream>>>(edst, esrc, ew, cur, sperm, wperm);

  // initial node features
  k_embed<<<NNODE, 128, 0, stream>>>(gfeat, tfeat, W0, b0, scale0, bufA);

  // 3 message-passing layers
  for (int i = 0; i < 3; i++) {
    const float* Wi = Wl + (size_t)i * HID * HID;
    const float* bi = bl + (size_t)i * HID;
    const float* si = scalel + i;
    if (i == 0)
      k_linear<0><<<(NNODE + 31) / 32, 256, 0, stream>>>(bufA, Wi, bi, si, bufB);
    else
      k_linear<1><<<(NNODE + 31) / 32, 256, 0, stream>>>(bufA, Wi, bi, si, bufB);
    k_gather<<<NNODE, 128, 0, stream>>>(bufB, off, sperm, wperm, bufA);
  }

  // segment mean + normalize
  k_final<<<NSEG, 128, 0, stream>>>(bufA, segids, outp);
}

// Round 6
// 949.680 us; speedup vs baseline: 3.1044x; 1.0957x over previous
//
#include <hip/hip_runtime.h>
#include <math.h>

#define HID    128
#define NTREE  6000
#define NGRAPH 144000
#define NNODE  150000
#define NEDGE  600000
#define NSEG   4096
#define AF     34
#define EPSF   1e-8f

#define SCAN_BLK   256
#define SCAN_ELEMS 1024
#define NSCAN ((NNODE + SCAN_ELEMS - 1) / SCAN_ELEMS)   // 147

// ---------------- reductions ----------------

__device__ __forceinline__ float waveReduceSum(float v) {
#pragma unroll
  for (int o = 32; o > 0; o >>= 1) v += __shfl_down(v, o, 64);
  return v;
}

// block of exactly 128 threads (2 waves)
__device__ __forceinline__ float blockReduce128(float v, float* red) {
  v = waveReduceSum(v);
  int w = threadIdx.x >> 6;
  if ((threadIdx.x & 63) == 0) red[w] = v;
  __syncthreads();
  float r = red[0] + red[1];
  __syncthreads();
  return r;
}

// ---------------- CSR build ----------------

__global__ void k_hist(const int* __restrict__ dst, int* __restrict__ deg) {
  int e = blockIdx.x * blockDim.x + threadIdx.x;
  if (e < NEDGE) atomicAdd(&deg[dst[e]], 1);
}

__global__ void k_scan1(const int* __restrict__ deg, int* __restrict__ off,
                        int* __restrict__ part) {
  __shared__ int s[SCAN_BLK];
  int b = blockIdx.x, t = threadIdx.x;
  int base = b * SCAN_ELEMS + t * 4;
  int v0 = 0, v1 = 0, v2 = 0, v3 = 0;
  if (base + 0 < NNODE) v0 = deg[base + 0];
  if (base + 1 < NNODE) v1 = deg[base + 1];
  if (base + 2 < NNODE) v2 = deg[base + 2];
  if (base + 3 < NNODE) v3 = deg[base + 3];
  int sum = v0 + v1 + v2 + v3;
  s[t] = sum;
  __syncthreads();
  for (int o = 1; o < SCAN_BLK; o <<= 1) {
    int x = (t >= o) ? s[t - o] : 0;
    __syncthreads();
    s[t] += x;
    __syncthreads();
  }
  int run = s[t] - sum;  // exclusive prefix for this thread within block
  run += v0; if (base + 0 < NNODE) off[base + 1] = run;
  run += v1; if (base + 1 < NNODE) off[base + 2] = run;
  run += v2; if (base + 2 < NNODE) off[base + 3] = run;
  run += v3; if (base + 3 < NNODE) off[base + 4] = run;
  if (t == SCAN_BLK - 1) part[b] = s[t];
  if (b == 0 && t == 0) off[0] = 0;
}

__global__ void k_scan2(int* part, int nb) {
  __shared__ int s[SCAN_BLK];
  int t = threadIdx.x;
  s[t] = (t < nb) ? part[t] : 0;
  __syncthreads();
  for (int o = 1; o < SCAN_BLK; o <<= 1) {
    int x = (t >= o) ? s[t - o] : 0;
    __syncthreads();
    s[t] += x;
    __syncthreads();
  }
  if (t < nb) part[t] = s[t];
}

__global__ void k_scan3(int* __restrict__ off, const int* __restrict__ part) {
  int b = blockIdx.x;
  if (b == 0) return;
  int add = part[b - 1];
  int base = b * SCAN_ELEMS + threadIdx.x * 4 + 1;
#pragma unroll
  for (int j = 0; j < 4; j++) {
    int idx = base + j;
    if (idx <= NNODE) off[idx] += add;
  }
}

__global__ void k_fill(const int* __restrict__ dst, const int* __restrict__ src,
                       const float* __restrict__ ew, int* __restrict__ cur,
                       int* __restrict__ sperm, float* __restrict__ wperm) {
  int e = blockIdx.x * blockDim.x + threadIdx.x;
  if (e < NEDGE) {
    int d = dst[e];
    int p = atomicAdd(&cur[d], 1);
    sperm[p] = src[e];
    wperm[p] = ew[e];
  }
}

// ---------------- embedding (expmap0 + lorentz_linear W0) ----------------
// Wave-per-row. Round-5 version (block-per-row, per-thread scattered W0 reads)
// ran 200us at 82% VALUBusy (~670 instr/wave vs ~150 useful). Here: W0 rows
// [lane] and [lane+64] are loop-invariant -> hoisted into 70 VGPRs once;
// gfe broadcast via v_readlane (SGPR folds into FMA, no LDS, no syncthreads);
// cosh/sinh from one expf (uniform, no divergence); coalesced stores.
// Tree rows handled by a d2d memcpy in kernel_launch.

__global__ __launch_bounds__(256) void k_embed(const float* __restrict__ gfeat,
                                               const float* __restrict__ W0,
                                               const float* __restrict__ b0,
                                               const float* __restrict__ scale0,
                                               float* __restrict__ xout) {
  const int lane = threadIdx.x & 63;
  const int gwave = blockIdx.x * (blockDim.x >> 6) + (threadIdx.x >> 6);
  const int nwaves = gridDim.x * (blockDim.x >> 6);

  // hoist W0 rows (lane) and (lane+64): 35 floats each, loop-invariant
  float wa[AF + 1], wb[AF + 1];
  {
    const float* ra = W0 + (size_t)lane * (AF + 1);
    const float* rb = W0 + (size_t)(lane + 64) * (AF + 1);
#pragma unroll
    for (int k = 0; k < AF + 1; ++k) { wa[k] = ra[k]; wb[k] = rb[k]; }
  }
  const float ba = b0[lane];
  const float bbv = b0[lane + 64];
  const float escale = expf(scale0[0]);

  for (int g = gwave; g < NGRAPH; g += nwaves) {
    // sp_k lives on lane k (k<34)
    float sv = (lane < AF) ? gfeat[(size_t)g * AF + lane] : 0.f;
    float ss = sv * sv;
#pragma unroll
    for (int m = 1; m <= 32; m <<= 1) ss += __shfl_xor(ss, m, 64);
    float nrm = fmaxf(sqrtf(ss), EPSF);
    float e = expf(nrm);
    float ei = 1.f / e;
    float coshv = 0.5f * (e + ei);          // uniform across wave
    float sh = 0.5f * (e - ei) / nrm;       // sinh(nrm)/nrm, uniform
    float gs = sh * sv;                     // lane k holds gfe[k+1]

    float acc0 = fmaf(wa[0], coshv, ba);
    float acc1 = fmaf(wb[0], coshv, bbv);
#pragma unroll
    for (int k = 1; k < AF + 1; ++k) {
      float gk = __int_as_float(
          __builtin_amdgcn_readlane(__float_as_int(gs), k - 1));
      acc0 = fmaf(wa[k], gk, acc0);
      acc1 = fmaf(wb[k], gk, acc1);
    }
    // ssum over dims 1..127 (exclude dim 0 = lane0's acc0)
    float part = ((lane == 0) ? 0.f : acc0 * acc0) + acc1 * acc1;
#pragma unroll
    for (int m = 1; m <= 32; m <<= 1) part += __shfl_xor(part, m, 64);
    float y0 = __int_as_float(__builtin_amdgcn_readlane(__float_as_int(acc0), 0));
    float timec = 1.f / (1.f + expf(-y0)) * escale + 1.1f;
    float s = (timec * timec - 1.f) / fmaxf(part, EPSF);
    float sq = sqrtf(s);
    float* orow = xout + (size_t)(NTREE + g) * HID;
    orow[lane] = (lane == 0) ? timec : acc0 * sq;
    orow[lane + 64] = acc1 * sq;
  }
}

// ---------------- lorentz_linear (128x128), register-tiled f32 ----------------
// Block 256 threads = 32 col-threads (tc, 4 cols each) x 8 row-groups (rg, 4 rows
// each). Block tile: 32 rows x 128 cols. Per-thread acc 4x4 = 16 VGPRs (no spill;
// round-2 8x4 tile + __launch_bounds__(256,4) spilled: VGPR=64, WRITE 1.8GB).
// LDS W layout: [col][32] with quad-slot XOR swizzle (k4 ^ ((col>>2)&7)) so a
// wave's 4 W-reads per k4-step cover all 32 banks (round-2 [k4][col][4] hit only
// banks {0,16} -> 16-way conflict, 1.56e7 SQ_LDS_BANK_CONFLICT).
// x-tile reads are half-wave broadcasts (conflict-free by definition).

template <int RELU>
__global__ __launch_bounds__(256) void k_linear(const float* __restrict__ in,
                                                const float* __restrict__ W,
                                                const float* __restrict__ b,
                                                const float* __restrict__ scale,
                                                float* __restrict__ out) {
  __shared__ __align__(16) float xs[32 * 32];   // [row][k]  4 KB
  __shared__ __align__(16) float wl[128 * 32];  // [col][k-swizzled] 16 KB

  const int tid = threadIdx.x;
  const int tc = tid & 31;        // col-thread: owns cols 4*tc .. 4*tc+3
  const int rg = tid >> 5;        // row-group: owns rows 4*rg .. 4*rg+3
  const int c0 = tc * 4;
  const int r0 = rg * 4;
  const int row_base = blockIdx.x * 32;
  const int swz = tc & 7;         // reader-side swizzle key

  float acc[4][4];
#pragma unroll
  for (int r = 0; r < 4; r++)
#pragma unroll
    for (int c = 0; c < 4; c++) acc[r][c] = 0.f;

  const int sr  = tid >> 3;         // 0..31 (staging row)
  const int skx = (tid & 7) * 4;    // 0..28 (staging k)
  const int wcol = tid >> 1;        // 0..127
  const int wq0  = (tid & 1) * 4;   // first k-quad this thread stages (0 or 4)
  const int wswz = (wcol >> 2) & 7; // writer-side swizzle key (== reader's tc&7)

  for (int kc = 0; kc < 4; ++kc) {
    __syncthreads();
    // stage x: 32 rows x 32 k (coalesced 128B per 8 lanes)
    {
      int row = row_base + sr;
      float4 v = make_float4(0.f, 0.f, 0.f, 0.f);
      if (row < NNODE) v = *(const float4*)&in[(size_t)row * HID + kc * 32 + skx];
      if (RELU) {
        v.x = fmaxf(v.x, 0.f); v.y = fmaxf(v.y, 0.f);
        v.z = fmaxf(v.z, 0.f); v.w = fmaxf(v.w, 0.f);
      }
      *(float4*)&xs[sr * 32 + skx] = v;
    }
    // stage W: 128 cols x 32 k, swizzled quad slots
    {
      const float* wsrc = W + (size_t)wcol * HID + kc * 32 + wq0 * 4;
#pragma unroll
      for (int q = 0; q < 4; ++q) {
        float4 v = *(const float4*)&wsrc[q * 4];
        int k4 = wq0 + q;
        *(float4*)&wl[wcol * 32 + ((k4 ^ wswz) << 2)] = v;
      }
    }
    __syncthreads();
    // compute: 8 k4-steps, 64 FMA per step per thread
#pragma unroll
    for (int k4 = 0; k4 < 8; ++k4) {
      float4 xv[4];
      float4 wv[4];
#pragma unroll
      for (int r = 0; r < 4; ++r)
        xv[r] = *(const float4*)&xs[(r0 + r) * 32 + k4 * 4];
#pragma unroll
      for (int c = 0; c < 4; ++c)
        wv[c] = *(const float4*)&wl[(c0 + c) * 32 + ((k4 ^ swz) << 2)];
#pragma unroll
      for (int r = 0; r < 4; ++r)
#pragma unroll
        for (int c = 0; c < 4; ++c)
          acc[r][c] += wv[c].x * xv[r].x + wv[c].y * xv[r].y +
                       wv[c].z * xv[r].z + wv[c].w * xv[r].w;
    }
  }

  // epilogue: per-row lorentz normalization (reduce across the 32 tc lanes)
  const float escale = expf(scale[0]);
  const float4 bb = *(const float4*)&b[c0];
#pragma unroll
  for (int r = 0; r < 4; ++r) {
    float y0v = acc[r][0] + bb.x;
    float y1v = acc[r][1] + bb.y;
    float y2v = acc[r][2] + bb.z;
    float y3v = acc[r][3] + bb.w;
    float part = y0v * y0v + y1v * y1v + y2v * y2v + y3v * y3v;
#pragma unroll
    for (int m = 1; m <= 16; m <<= 1) part += __shfl_xor(part, m, 64);
    // col 0 lives in tc==0 of my half-wave
    float y0 = __shfl(y0v, (threadIdx.x & 32), 64);
    float timec = 1.f / (1.f + expf(-y0)) * escale + 1.1f;
    float ssum = part - y0 * y0;
    float s = (timec * timec - 1.f) / fmaxf(ssum, EPSF);
    float sq = sqrtf(s);
    int row = row_base + r0 + r;
    if (row < NNODE) {
      float4 o;
      o.x = (tc == 0) ? timec : y0v * sq;
      o.y = y1v * sq;
      o.z = y2v * sq;
      o.w = y3v * sq;
      *(float4*)&out[(size_t)row * HID + c0] = o;
    }
  }
}

// ---------------- CSR gather + fused centroid normalize ----------------

__global__ void k_gather(const float* __restrict__ h, const int* __restrict__ off,
                         const int* __restrict__ sperm, const float* __restrict__ wperm,
                         float* __restrict__ out) {
  __shared__ float red[2];
  int n = blockIdx.x;
  int t = threadIdx.x;
  int e0 = off[n], e1 = off[n + 1];
  float acc = 0.f;
  for (int e = e0; e < e1; ++e) {
    int s = sperm[e];
    float w = wperm[e];
    acc += w * h[(size_t)s * HID + t];
  }
  float part = (t == 0) ? acc * acc : -acc * acc;
  float d = blockReduce128(part, red);
  float denom = sqrtf(fmaxf(fabsf(d), EPSF));
  out[(size_t)n * HID + t] = acc / denom;
}

// ---------------- final segment mean + normalize ----------------

__device__ __forceinline__ int lowerBound(const int* __restrict__ a, int n, int key) {
  int lo = 0, hi = n;
  while (lo < hi) {
    int mid = (lo + hi) >> 1;
    if (a[mid] < key) lo = mid + 1; else hi = mid;
  }
  return lo;
}

__global__ void k_final(const float* __restrict__ h, const int* __restrict__ seg,
                        float* __restrict__ out) {
  __shared__ float red[2];
  int bseg = blockIdx.x;
  int t = threadIdx.x;
  int lo = lowerBound(seg, NGRAPH, bseg);
  int hi = lowerBound(seg, NGRAPH, bseg + 1);
  float acc = 0.f;
  for (int r = lo; r < hi; ++r) acc += h[(size_t)(NTREE + r) * HID + t];
  float cnt = (float)(hi - lo);
  float ave = acc / fmaxf(cnt, 1.f);
  float part = (t == 0) ? ave * ave : -ave * ave;
  float d = blockReduce128(part, red);
  float denom = sqrtf(fmaxf(fabsf(d), EPSF));
  out[bseg * HID + t] = ave / denom;
}

// ---------------- launch ----------------

extern "C" void kernel_launch(void* const* d_in, const int* in_sizes, int n_in,
                              void* d_out, int out_size, void* d_ws, size_t ws_size,
                              hipStream_t stream) {
  const float* gfeat  = (const float*)d_in[0];
  const float* tfeat  = (const float*)d_in[1];
  const float* ew     = (const float*)d_in[2];
  const float* W0     = (const float*)d_in[3];
  const float* b0     = (const float*)d_in[4];
  const float* scale0 = (const float*)d_in[5];
  const float* Wl     = (const float*)d_in[6];
  const float* bl     = (const float*)d_in[7];
  const float* scalel = (const float*)d_in[8];
  const int* esrc     = (const int*)d_in[9];
  const int* edst     = (const int*)d_in[10];
  const int* segids   = (const int*)d_in[11];
  float* outp = (float*)d_out;

  char* ws = (char*)d_ws;
  size_t o = 0;
  auto take = [&](size_t bytes) -> char* {
    char* p = ws + o;
    o = (o + bytes + 255) & ~(size_t)255;
    return p;
  };
  int*   off   = (int*)take((NNODE + 1) * sizeof(int));
  int*   cur   = (int*)take(NNODE * sizeof(int));
  int*   sperm = (int*)take(NEDGE * sizeof(int));
  float* wperm = (float*)take(NEDGE * sizeof(float));
  int*   part  = (int*)take(SCAN_BLK * sizeof(int));
  float* bufA  = (float*)take((size_t)NNODE * HID * sizeof(float));
  float* bufB  = (float*)take((size_t)NNODE * HID * sizeof(float));
  (void)ws_size; (void)in_sizes; (void)n_in; (void)out_size;

  // CSR build (by destination)
  hipMemsetAsync(cur, 0, NNODE * sizeof(int), stream);
  k_hist<<<(NEDGE + 255) / 256, 256, 0, stream>>>(edst, cur);
  k_scan1<<<NSCAN, SCAN_BLK, 0, stream>>>(cur, off, part);
  k_scan2<<<1, SCAN_BLK, 0, stream>>>(part, NSCAN);
  k_scan3<<<NSCAN, SCAN_BLK, 0, stream>>>(off, part);
  hipMemcpyAsync(cur, off, NNODE * sizeof(int), hipMemcpyDeviceToDevice, stream);
  k_fill<<<(NEDGE + 255) / 256, 256, 0, stream>>>(edst, esrc, ew, cur, sperm, wperm);

  // initial node features: tree rows are a straight copy; graph rows computed
  hipMemcpyAsync(bufA, tfeat, (size_t)NTREE * HID * sizeof(float),
                 hipMemcpyDeviceToDevice, stream);
  k_embed<<<1024, 256, 0, stream>>>(gfeat, W0, b0, scale0, bufA);

  // 3 message-passing layers
  for (int i = 0; i < 3; i++) {
    const float* Wi = Wl + (size_t)i * HID * HID;
    const float* bi = bl + (size_t)i * HID;
    const float* si = scalel + i;
    if (i == 0)
      k_linear<0><<<(NNODE + 31) / 32, 256, 0, stream>>>(bufA, Wi, bi, si, bufB);
    else
      k_linear<1><<<(NNODE + 31) / 32, 256, 0, stream>>>(bufA, Wi, bi, si, bufB);
    k_gather<<<NNODE, 128, 0, stream>>>(bufB, off, sperm, wperm, bufA);
  }

  // segment mean + normalize
  k_final<<<NSEG, 128, 0, stream>>>(bufA, segids, outp);
}

// Round 9
// 921.995 us; speedup vs baseline: 3.1976x; 1.0300x over previous
//
#include <hip/hip_runtime.h>
#include <math.h>

#define HID    128
#define NTREE  6000
#define NGRAPH 144000
#define NNODE  150000
#define NEDGE  600000
#define NSEG   4096
#define AF     34
#define EPSF   1e-8f

#define SCAN_BLK   256
#define SCAN_ELEMS 1024
#define NSCAN ((NNODE + SCAN_ELEMS - 1) / SCAN_ELEMS)   // 147

#define XSTRIDE 36   // xs row stride in floats: 36*4B=144B, 16B-aligned, %32!=0

// ---------------- reductions ----------------

__device__ __forceinline__ float waveReduceSum(float v) {
#pragma unroll
  for (int o = 32; o > 0; o >>= 1) v += __shfl_down(v, o, 64);
  return v;
}

// block of exactly 128 threads (2 waves)
__device__ __forceinline__ float blockReduce128(float v, float* red) {
  v = waveReduceSum(v);
  int w = threadIdx.x >> 6;
  if ((threadIdx.x & 63) == 0) red[w] = v;
  __syncthreads();
  float r = red[0] + red[1];
  __syncthreads();
  return r;
}

// ---------------- CSR build ----------------

__global__ void k_hist(const int* __restrict__ dst, int* __restrict__ deg) {
  int e = blockIdx.x * blockDim.x + threadIdx.x;
  if (e < NEDGE) atomicAdd(&deg[dst[e]], 1);
}

__global__ void k_scan1(const int* __restrict__ deg, int* __restrict__ off,
                        int* __restrict__ part) {
  __shared__ int s[SCAN_BLK];
  int b = blockIdx.x, t = threadIdx.x;
  int base = b * SCAN_ELEMS + t * 4;
  int v0 = 0, v1 = 0, v2 = 0, v3 = 0;
  if (base + 0 < NNODE) v0 = deg[base + 0];
  if (base + 1 < NNODE) v1 = deg[base + 1];
  if (base + 2 < NNODE) v2 = deg[base + 2];
  if (base + 3 < NNODE) v3 = deg[base + 3];
  int sum = v0 + v1 + v2 + v3;
  s[t] = sum;
  __syncthreads();
  for (int o = 1; o < SCAN_BLK; o <<= 1) {
    int x = (t >= o) ? s[t - o] : 0;
    __syncthreads();
    s[t] += x;
    __syncthreads();
  }
  int run = s[t] - sum;  // exclusive prefix for this thread within block
  run += v0; if (base + 0 < NNODE) off[base + 1] = run;
  run += v1; if (base + 1 < NNODE) off[base + 2] = run;
  run += v2; if (base + 2 < NNODE) off[base + 3] = run;
  run += v3; if (base + 3 < NNODE) off[base + 4] = run;
  if (t == SCAN_BLK - 1) part[b] = s[t];
  if (b == 0 && t == 0) off[0] = 0;
}

__global__ void k_scan2(int* part, int nb) {
  __shared__ int s[SCAN_BLK];
  int t = threadIdx.x;
  s[t] = (t < nb) ? part[t] : 0;
  __syncthreads();
  for (int o = 1; o < SCAN_BLK; o <<= 1) {
    int x = (t >= o) ? s[t - o] : 0;
    __syncthreads();
    s[t] += x;
    __syncthreads();
  }
  if (t < nb) part[t] = s[t];
}

__global__ void k_scan3(int* __restrict__ off, const int* __restrict__ part) {
  int b = blockIdx.x;
  if (b == 0) return;
  int add = part[b - 1];
  int base = b * SCAN_ELEMS + threadIdx.x * 4 + 1;
#pragma unroll
  for (int j = 0; j < 4; j++) {
    int idx = base + j;
    if (idx <= NNODE) off[idx] += add;
  }
}

__global__ void k_fill(const int* __restrict__ dst, const int* __restrict__ src,
                       const float* __restrict__ ew, int* __restrict__ cur,
                       int* __restrict__ sperm, float* __restrict__ wperm) {
  int e = blockIdx.x * blockDim.x + threadIdx.x;
  if (e < NEDGE) {
    int d = dst[e];
    int p = atomicAdd(&cur[d], 1);
    sperm[p] = src[e];
    wperm[p] = ew[e];
  }
}

// ---------------- embedding (expmap0 + lorentz_linear W0) ----------------
// Wave-per-row; W0 rows hoisted to VGPRs; readlane broadcasts; single expf.

__global__ __launch_bounds__(256) void k_embed(const float* __restrict__ gfeat,
                                               const float* __restrict__ W0,
                                               const float* __restrict__ b0,
                                               const float* __restrict__ scale0,
                                               float* __restrict__ xout) {
  const int lane = threadIdx.x & 63;
  const int gwave = blockIdx.x * (blockDim.x >> 6) + (threadIdx.x >> 6);
  const int nwaves = gridDim.x * (blockDim.x >> 6);

  float wa[AF + 1], wb[AF + 1];
  {
    const float* ra = W0 + (size_t)lane * (AF + 1);
    const float* rb = W0 + (size_t)(lane + 64) * (AF + 1);
#pragma unroll
    for (int k = 0; k < AF + 1; ++k) { wa[k] = ra[k]; wb[k] = rb[k]; }
  }
  const float ba = b0[lane];
  const float bbv = b0[lane + 64];
  const float escale = expf(scale0[0]);

  for (int g = gwave; g < NGRAPH; g += nwaves) {
    float sv = (lane < AF) ? gfeat[(size_t)g * AF + lane] : 0.f;
    float ss = sv * sv;
#pragma unroll
    for (int m = 1; m <= 32; m <<= 1) ss += __shfl_xor(ss, m, 64);
    float nrm = fmaxf(sqrtf(ss), EPSF);
    float e = expf(nrm);
    float ei = 1.f / e;
    float coshv = 0.5f * (e + ei);
    float sh = 0.5f * (e - ei) / nrm;
    float gs = sh * sv;

    float acc0 = fmaf(wa[0], coshv, ba);
    float acc1 = fmaf(wb[0], coshv, bbv);
#pragma unroll
    for (int k = 1; k < AF + 1; ++k) {
      float gk = __int_as_float(
          __builtin_amdgcn_readlane(__float_as_int(gs), k - 1));
      acc0 = fmaf(wa[k], gk, acc0);
      acc1 = fmaf(wb[k], gk, acc1);
    }
    float part = ((lane == 0) ? 0.f : acc0 * acc0) + acc1 * acc1;
#pragma unroll
    for (int m = 1; m <= 32; m <<= 1) part += __shfl_xor(part, m, 64);
    float y0 = __int_as_float(__builtin_amdgcn_readlane(__float_as_int(acc0), 0));
    float timec = 1.f / (1.f + expf(-y0)) * escale + 1.1f;
    float s = (timec * timec - 1.f) / fmaxf(part, EPSF);
    float sq = sqrtf(s);
    float* orow = xout + (size_t)(NTREE + g) * HID;
    orow[lane] = (lane == 0) ? timec : acc0 * sq;
    orow[lane + 64] = acc1 * sq;
  }
}

// ---------------- lorentz_linear (128x128), register-tiled f32 ----------------
// Round-6 forensics: SQ_LDS_BANK_CONFLICT=1.68e7 came from (a) W-STAGING WRITES
// (8 consecutive lanes wrote only 2 bank-quads: bank=4*(k4^wswz), k4 in {q,q+4}
// -> 4-way on every ds_write_b128) and (b) xs broadcast reads (2 addrs, 4 rows
// * 32 floats apart = same bank-quad). Fixes:
//  - staging k4 = 4h + (q ^ (c&3)): 8 lanes' bank-quads = {q^0,4+q^0,...,q^3,
//    4+q^3} = all 8 -> conflict-free writes; each (col,k4) still written once.
//  - xs row stride 36 (144B, 16B-aligned, !=0 mod 32): the 2 broadcast addrs
//    now land on disjoint bank-quads.
// W reads were already conflict-free: bank = 4*(k4^tc), tc&7 covers 0..7.

template <int RELU>
__global__ __launch_bounds__(256) void k_linear(const float* __restrict__ in,
                                                const float* __restrict__ W,
                                                const float* __restrict__ b,
                                                const float* __restrict__ scale,
                                                float* __restrict__ out) {
  __shared__ __align__(16) float xs[32 * XSTRIDE];  // [row][k pad-36] 4.6 KB
  __shared__ __align__(16) float wl[128 * 32];      // [col][k-swizzled] 16 KB

  const int tid = threadIdx.x;
  const int tc = tid & 31;        // col-thread: owns cols 4*tc .. 4*tc+3
  const int rg = tid >> 5;        // row-group: owns rows 4*rg .. 4*rg+3
  const int c0 = tc * 4;
  const int r0 = rg * 4;
  const int row_base = blockIdx.x * 32;
  const int swz = tc & 7;         // reader-side swizzle key

  float acc[4][4];
#pragma unroll
  for (int r = 0; r < 4; r++)
#pragma unroll
    for (int c = 0; c < 4; c++) acc[r][c] = 0.f;

  const int sr  = tid >> 3;         // 0..31 (staging row)
  const int skx = (tid & 7) * 4;    // 0..28 (staging k)
  const int wcol = tid >> 1;        // 0..127
  const int wh   = (tid & 1) * 4;   // k-quad half: 0 or 4
  const int wc3  = wcol & 3;        // xor key so 8 lanes cover all bank-quads
  const int wswz = (wcol >> 2) & 7; // writer-side swizzle key (== reader's tc&7)

  for (int kc = 0; kc < 4; ++kc) {
    __syncthreads();
    // stage x: 32 rows x 32 k (coalesced 128B per 8 lanes)
    {
      int row = row_base + sr;
      float4 v = make_float4(0.f, 0.f, 0.f, 0.f);
      if (row < NNODE) v = *(const float4*)&in[(size_t)row * HID + kc * 32 + skx];
      if (RELU) {
        v.x = fmaxf(v.x, 0.f); v.y = fmaxf(v.y, 0.f);
        v.z = fmaxf(v.z, 0.f); v.w = fmaxf(v.w, 0.f);
      }
      *(float4*)&xs[sr * XSTRIDE + skx] = v;
    }
    // stage W: 128 cols x 32 k, swizzled quad slots, conflict-free writes
    {
      const float* wsrc = W + (size_t)wcol * HID + kc * 32;
#pragma unroll
      for (int q = 0; q < 4; ++q) {
        int k4 = wh + (q ^ wc3);
        float4 v = *(const float4*)&wsrc[k4 * 4];
        *(float4*)&wl[wcol * 32 + ((k4 ^ wswz) << 2)] = v;
      }
    }
    __syncthreads();
    // compute: 8 k4-steps, 64 FMA per step per thread
#pragma unroll
    for (int k4 = 0; k4 < 8; ++k4) {
      float4 xv[4];
      float4 wv[4];
#pragma unroll
      for (int r = 0; r < 4; ++r)
        xv[r] = *(const float4*)&xs[(r0 + r) * XSTRIDE + k4 * 4];
#pragma unroll
      for (int c = 0; c < 4; ++c)
        wv[c] = *(const float4*)&wl[(c0 + c) * 32 + ((k4 ^ swz) << 2)];
#pragma unroll
      for (int r = 0; r < 4; ++r)
#pragma unroll
        for (int c = 0; c < 4; ++c)
          acc[r][c] += wv[c].x * xv[r].x + wv[c].y * xv[r].y +
                       wv[c].z * xv[r].z + wv[c].w * xv[r].w;
    }
  }

  // epilogue: per-row lorentz normalization (reduce across the 32 tc lanes)
  const float escale = expf(scale[0]);
  const float4 bb = *(const float4*)&b[c0];
#pragma unroll
  for (int r = 0; r < 4; ++r) {
    float y0v = acc[r][0] + bb.x;
    float y1v = acc[r][1] + bb.y;
    float y2v = acc[r][2] + bb.z;
    float y3v = acc[r][3] + bb.w;
    float part = y0v * y0v + y1v * y1v + y2v * y2v + y3v * y3v;
#pragma unroll
    for (int m = 1; m <= 16; m <<= 1) part += __shfl_xor(part, m, 64);
    // col 0 lives in tc==0 of my half-wave
    float y0 = __shfl(y0v, (threadIdx.x & 32), 64);
    float timec = 1.f / (1.f + expf(-y0)) * escale + 1.1f;
    float ssum = part - y0 * y0;
    float s = (timec * timec - 1.f) / fmaxf(ssum, EPSF);
    float sq = sqrtf(s);
    int row = row_base + r0 + r;
    if (row < NNODE) {
      float4 o;
      o.x = (tc == 0) ? timec : y0v * sq;
      o.y = y1v * sq;
      o.z = y2v * sq;
      o.w = y3v * sq;
      *(float4*)&out[(size_t)row * HID + c0] = o;
    }
  }
}

// ---------------- CSR gather + fused centroid normalize ----------------

__global__ void k_gather(const float* __restrict__ h, const int* __restrict__ off,
                         const int* __restrict__ sperm, const float* __restrict__ wperm,
                         float* __restrict__ out) {
  __shared__ float red[2];
  int n = blockIdx.x;
  int t = threadIdx.x;
  int e0 = off[n], e1 = off[n + 1];
  float acc = 0.f;
  for (int e = e0; e < e1; ++e) {
    int s = sperm[e];
    float w = wperm[e];
    acc += w * h[(size_t)s * HID + t];
  }
  float part = (t == 0) ? acc * acc : -acc * acc;
  float d = blockReduce128(part, red);
  float denom = sqrtf(fmaxf(fabsf(d), EPSF));
  out[(size_t)n * HID + t] = acc / denom;
}

// ---------------- final segment mean + normalize ----------------

__device__ __forceinline__ int lowerBound(const int* __restrict__ a, int n, int key) {
  int lo = 0, hi = n;
  while (lo < hi) {
    int mid = (lo + hi) >> 1;
    if (a[mid] < key) lo = mid + 1; else hi = mid;
  }
  return lo;
}

__global__ void k_final(const float* __restrict__ h, const int* __restrict__ seg,
                        float* __restrict__ out) {
  __shared__ float red[2];
  int bseg = blockIdx.x;
  int t = threadIdx.x;
  int lo = lowerBound(seg, NGRAPH, bseg);
  int hi = lowerBound(seg, NGRAPH, bseg + 1);
  float acc = 0.f;
  for (int r = lo; r < hi; ++r) acc += h[(size_t)(NTREE + r) * HID + t];
  float cnt = (float)(hi - lo);
  float ave = acc / fmaxf(cnt, 1.f);
  float part = (t == 0) ? ave * ave : -ave * ave;
  float d = blockReduce128(part, red);
  float denom = sqrtf(fmaxf(fabsf(d), EPSF));
  out[bseg * HID + t] = ave / denom;
}

// ---------------- launch ----------------

extern "C" void kernel_launch(void* const* d_in, const int* in_sizes, int n_in,
                              void* d_out, int out_size, void* d_ws, size_t ws_size,
                              hipStream_t stream) {
  const float* gfeat  = (const float*)d_in[0];
  const float* tfeat  = (const float*)d_in[1];
  const float* ew     = (const float*)d_in[2];
  const float* W0     = (const float*)d_in[3];
  const float* b0     = (const float*)d_in[4];
  const float* scale0 = (const float*)d_in[5];
  const float* Wl     = (const float*)d_in[6];
  const float* bl     = (const float*)d_in[7];
  const float* scalel = (const float*)d_in[8];
  const int* esrc     = (const int*)d_in[9];
  const int* edst     = (const int*)d_in[10];
  const int* segids   = (const int*)d_in[11];
  float* outp = (float*)d_out;

  char* ws = (char*)d_ws;
  size_t o = 0;
  auto take = [&](size_t bytes) -> char* {
    char* p = ws + o;
    o = (o + bytes + 255) & ~(size_t)255;
    return p;
  };
  int*   off   = (int*)take((NNODE + 1) * sizeof(int));
  int*   cur   = (int*)take(NNODE * sizeof(int));
  int*   sperm = (int*)take(NEDGE * sizeof(int));
  float* wperm = (float*)take(NEDGE * sizeof(float));
  int*   part  = (int*)take(SCAN_BLK * sizeof(int));
  float* bufA  = (float*)take((size_t)NNODE * HID * sizeof(float));
  float* bufB  = (float*)take((size_t)NNODE * HID * sizeof(float));
  (void)ws_size; (void)in_sizes; (void)n_in; (void)out_size;

  // CSR build (by destination)
  hipMemsetAsync(cur, 0, NNODE * sizeof(int), stream);
  k_hist<<<(NEDGE + 255) / 256, 256, 0, stream>>>(edst, cur);
  k_scan1<<<NSCAN, SCAN_BLK, 0, stream>>>(cur, off, part);
  k_scan2<<<1, SCAN_BLK, 0, stream>>>(part, NSCAN);
  k_scan3<<<NSCAN, SCAN_BLK, 0, stream>>>(off, part);
  hipMemcpyAsync(cur, off, NNODE * sizeof(int), hipMemcpyDeviceToDevice, stream);
  k_fill<<<(NEDGE + 255) / 256, 256, 0, stream>>>(edst, esrc, ew, cur, sperm, wperm);

  // initial node features: tree rows are a straight copy; graph rows computed
  hipMemcpyAsync(bufA, tfeat, (size_t)NTREE * HID * sizeof(float),
                 hipMemcpyDeviceToDevice, stream);
  k_embed<<<1024, 256, 0, stream>>>(gfeat, W0, b0, scale0, bufA);

  // 3 message-passing layers
  for (int i = 0; i < 3; i++) {
    const float* Wi = Wl + (size_t)i * HID * HID;
    const float* bi = bl + (size_t)i * HID;
    const float* si = scalel + i;
    if (i == 0)
      k_linear<0><<<(NNODE + 31) / 32, 256, 0, stream>>>(bufA, Wi, bi, si, bufB);
    else
      k_linear<1><<<(NNODE + 31) / 32, 256, 0, stream>>>(bufA, Wi, bi, si, bufB);
    k_gather<<<NNODE, 128, 0, stream>>>(bufB, off, sperm, wperm, bufA);
  }

  // segment mean + normalize
  k_final<<<NSEG, 128, 0, stream>>>(bufA, segids, outp);
}